// Round 4
// baseline (365.099 us; speedup 1.0000x reference)
//
#include <hip/hip_runtime.h>

typedef unsigned short u16;
typedef u16 u16x8 __attribute__((ext_vector_type(8)));
typedef __bf16 bf16;
typedef bf16 bf16x8 __attribute__((ext_vector_type(8)));
typedef float f32x4 __attribute__((ext_vector_type(4)));

__device__ __forceinline__ float bf2f(u16 v) {
  union { unsigned u; float f; } x; x.u = ((unsigned)v) << 16; return x.f;
}
__device__ __forceinline__ u16 f2bf(float f) {
  union { float f; unsigned u; } x; x.f = f;
  unsigned u = x.u;
  u += 0x7fffu + ((u >> 16) & 1u);   // RNE
  return (u16)(u >> 16);
}

// ---------------- convert small fp32 inputs to canonical bf16 ----------------
// dstW: W_kds(32768) ++ W_vds(32768); dstB: bq,bk,bv,bout (768 each)
__global__ __launch_bounds__(256) void convert_k(
    const float* __restrict__ wk, const float* __restrict__ wv,
    const float* __restrict__ b0, const float* __restrict__ b1,
    const float* __restrict__ b2, const float* __restrict__ b3,
    u16* __restrict__ dstW, u16* __restrict__ dstB) {
  const int i = blockIdx.x * 256 + threadIdx.x;   // 268*256 = 68608 exactly
  if (i < 32768)      dstW[i] = f2bf(wk[i]);
  else if (i < 65536) dstW[i] = f2bf(wv[i - 32768]);
  else {
    int j = i - 65536, s = j / 768, si = j % 768;
    const float* src = (s == 0) ? b0 : (s == 1) ? b1 : (s == 2) ? b2 : b3;
    dstB[j] = f2bf(src[si]);
  }
}

// ---------------- 768x768 fp32 weight transpose -> bf16 (4 weights) ----------------
__global__ __launch_bounds__(256) void transpose4_k(
    const float* __restrict__ w0, const float* __restrict__ w1,
    const float* __restrict__ w2, const float* __restrict__ w3,
    u16* __restrict__ out) {
  const float* W = (blockIdx.z == 0) ? w0 : (blockIdx.z == 1) ? w1 : (blockIdx.z == 2) ? w2 : w3;
  u16* O = out + (size_t)blockIdx.z * 768 * 768;
  __shared__ u16 T[64][72];
  const int t = threadIdx.x;
  const int r0 = blockIdx.x * 64, c0 = blockIdx.y * 64;
  #pragma unroll
  for (int p = 0; p < 2; ++p) {
    int v = t + p * 256;
    int r = v / 8, c = (v % 8) * 8;
    f32x4 x0 = *(const f32x4*)&W[(size_t)(r0 + r) * 768 + c0 + c];
    f32x4 x1 = *(const f32x4*)&W[(size_t)(r0 + r) * 768 + c0 + c + 4];
    #pragma unroll
    for (int i = 0; i < 4; ++i) { T[r][c + i] = f2bf(x0[i]); T[r][c + 4 + i] = f2bf(x1[i]); }
  }
  __syncthreads();
  #pragma unroll
  for (int p = 0; p < 2; ++p) {
    int v = t + p * 256;
    int r = v / 8, c = (v % 8) * 8;
    u16x8 tv;
    #pragma unroll
    for (int i = 0; i < 8; ++i) tv[i] = T[c + i][r];
    *(u16x8*)&O[(size_t)(c0 + r) * 768 + r0 + c] = tv;
  }
}

// ---------------- generic MFMA GEMM, bf16 compute, per-operand dtype ----------------
// C[M,N] = act(A[M,K] @ B + bias); A row-major (lda), C row-major (ldc).
// NN=false: B is Bt[N,K] row-major. NN=true: B is [K,N] row-major (BN=128,BK=32 only).
// ACT: 0 none, 1 elu(x)+1, 2 multiply by rowscale[row*rs_stride].
// AF32/BF32/OF32: operand is fp32 (else bf16-as-u16). Batch offsets are in ELEMENTS
// of the operand's dtype and are applied to the dtype-correct pointer (round-3 bugfix).
template<int BM, int BN, int BK, int WM, int WN, bool NN, int ACT,
         bool AF32, bool BF32, bool OF32>
__global__ __launch_bounds__(256) void gemm_k(
    const void* __restrict__ Araw, int lda,
    const void* __restrict__ Braw, int ldb,
    void* __restrict__ Craw, int ldc,
    const u16* __restrict__ bias,
    const float* __restrict__ rowscale, int rs_stride,
    int K, int nDiv,
    long long offA_b, long long offA_n,
    long long offB_b, long long offB_n,
    long long offC_b, long long offC_n,
    long long offS_b, long long offS_n)
{
  constexpr int LDSK = BK + 8;
  __shared__ u16 As[BM][LDSK];
  __shared__ u16 Bs[BN][LDSK];

  const int z  = blockIdx.z;
  const int bb = z / nDiv, ni = z % nDiv;
  const long long dA = bb * offA_b + ni * offA_n;
  const long long dB = bb * offB_b + ni * offB_n;
  const long long dC = bb * offC_b + ni * offC_n;
  const u16*   A16 = AF32 ? nullptr : ((const u16*)Araw) + dA;
  const float* A32 = AF32 ? ((const float*)Araw) + dA : nullptr;
  const u16*   B16 = BF32 ? nullptr : ((const u16*)Braw) + dB;
  const float* B32 = BF32 ? ((const float*)Braw) + dB : nullptr;
  u16*   C16 = OF32 ? nullptr : ((u16*)Craw) + dC;
  float* C32 = OF32 ? ((float*)Craw) + dC : nullptr;
  const float* rs = nullptr;
  if constexpr (ACT == 2) rs = rowscale + bb * offS_b + ni * offS_n;

  const int mt = blockIdx.x * BM;
  const int nt = blockIdx.y * BN;
  const int t = threadIdx.x;
  const int wave = t >> 6, lane = t & 63;
  constexpr int WAVES_N = BN / WN;
  const int wm = (wave / WAVES_N) * WM;
  const int wn = (wave % WAVES_N) * WN;
  constexpr int FM = WM / 16, FN = WN / 16;
  const int lrow = lane & 15, quad = lane >> 4;

  f32x4 acc[FM][FN] = {};

  for (int k0 = 0; k0 < K; k0 += BK) {
    __syncthreads();
    // ---- stage A tile [BM x BK] ----
    #pragma unroll
    for (int p = 0; p < (BM * BK / 8) / 256; ++p) {
      int v = t + p * 256;
      int r = v / (BK / 8);
      int c = (v % (BK / 8)) * 8;
      size_t idx = (size_t)(mt + r) * lda + k0 + c;
      if constexpr (!AF32) {
        *(u16x8*)&As[r][c] = *(const u16x8*)&A16[idx];
      } else {
        f32x4 x0 = *(const f32x4*)&A32[idx];
        f32x4 x1 = *(const f32x4*)&A32[idx + 4];
        u16x8 w;
        #pragma unroll
        for (int i = 0; i < 4; ++i) { w[i] = f2bf(x0[i]); w[4 + i] = f2bf(x1[i]); }
        *(u16x8*)&As[r][c] = w;
      }
    }
    // ---- stage B tile -> Bs[n][k] ----
    if constexpr (!NN) {
      #pragma unroll
      for (int p = 0; p < (BN * BK / 8) / 256; ++p) {
        int v = t + p * 256;
        int r = v / (BK / 8);
        int c = (v % (BK / 8)) * 8;
        size_t idx = (size_t)(nt + r) * ldb + k0 + c;
        if constexpr (!BF32) {
          *(u16x8*)&Bs[r][c] = *(const u16x8*)&B16[idx];
        } else {
          f32x4 x0 = *(const f32x4*)&B32[idx];
          f32x4 x1 = *(const f32x4*)&B32[idx + 4];
          u16x8 w;
          #pragma unroll
          for (int i = 0; i < 4; ++i) { w[i] = f2bf(x0[i]); w[4 + i] = f2bf(x1[i]); }
          *(u16x8*)&Bs[r][c] = w;
        }
      }
    } else {
      static_assert(!NN || (BN == 128 && BK == 32), "NN staging is fixed-shape");
      int n  = t & 127;
      int kh = (t >> 7) * 16;
      u16x8 t0, t1;
      if constexpr (!BF32) {
        #pragma unroll
        for (int i = 0; i < 8; ++i) t0[i] = B16[(size_t)(k0 + kh + i) * ldb + nt + n];
        #pragma unroll
        for (int i = 0; i < 8; ++i) t1[i] = B16[(size_t)(k0 + kh + 8 + i) * ldb + nt + n];
      } else {
        #pragma unroll
        for (int i = 0; i < 8; ++i) t0[i] = f2bf(B32[(size_t)(k0 + kh + i) * ldb + nt + n]);
        #pragma unroll
        for (int i = 0; i < 8; ++i) t1[i] = f2bf(B32[(size_t)(k0 + kh + 8 + i) * ldb + nt + n]);
      }
      *(u16x8*)&Bs[n][kh]     = t0;
      *(u16x8*)&Bs[n][kh + 8] = t1;
    }
    __syncthreads();

    // ---- fragments + MFMA (16x16x32 bf16) ----
    bf16x8 av[FM], bv[FN];
    #pragma unroll
    for (int i = 0; i < FM; ++i) av[i] = *(const bf16x8*)&As[wm + i * 16 + lrow][quad * 8];
    #pragma unroll
    for (int j = 0; j < FN; ++j) bv[j] = *(const bf16x8*)&Bs[wn + j * 16 + lrow][quad * 8];
    #pragma unroll
    for (int i = 0; i < FM; ++i)
      #pragma unroll
      for (int j = 0; j < FN; ++j)
        acc[i][j] = __builtin_amdgcn_mfma_f32_16x16x32_bf16(av[i], bv[j], acc[i][j], 0, 0, 0);
  }

  // ---- epilogue: C/D layout col=lane&15, row=quad*4+reg ----
  #pragma unroll
  for (int i = 0; i < FM; ++i) {
    #pragma unroll
    for (int j = 0; j < FN; ++j) {
      const int col = nt + wn + j * 16 + lrow;
      float badd = bias ? bf2f(bias[col]) : 0.0f;
      #pragma unroll
      for (int r = 0; r < 4; ++r) {
        const int row = mt + wm + i * 16 + quad * 4 + r;
        float v = acc[i][j][r] + badd;
        if constexpr (ACT == 1) v = v > 0.0f ? v + 1.0f : __expf(v);
        if constexpr (ACT == 2) v *= rs[(size_t)row * rs_stride];
        if constexpr (OF32) C32[(size_t)row * ldc + col] = v;
        else                C16[(size_t)row * ldc + col] = f2bf(v);
      }
    }
  }
}

// ---------------- per-(b,n) KV state: sT[h][d] = sum_k phi_k[k][d]*v[k][h]; z[d] ----------------
__global__ __launch_bounds__(256) void kv_state_k(
    const u16* __restrict__ phi_k, const u16* __restrict__ vals,
    u16* __restrict__ sT, float* __restrict__ z)
{
  __shared__ float pk[64][65];
  __shared__ float vv[64][65];
  const int x = blockIdx.x;          // b*12 + n
  const int b = x / 12, n = x % 12;
  const int t = threadIdx.x;
  const u16* pkg = phi_k + (size_t)b * 64 * 768 + n * 64;
  const u16* vvg = vals  + (size_t)b * 64 * 768 + n * 64;
  #pragma unroll
  for (int p = 0; p < 2; ++p) {
    int v = t + p * 256;
    int r = v / 8, c = (v % 8) * 8;
    u16x8 a  = *(const u16x8*)&pkg[(size_t)r * 768 + c];
    u16x8 bq = *(const u16x8*)&vvg[(size_t)r * 768 + c];
    #pragma unroll
    for (int i = 0; i < 8; ++i) { pk[r][c + i] = bf2f(a[i]); vv[r][c + i] = bf2f(bq[i]); }
  }
  __syncthreads();
  const int d0 = (t >> 4) * 4, h0 = (t & 15) * 4;
  float s4[4][4] = {};
  for (int k = 0; k < 64; ++k) {
    float pv[4], vb[4];
    #pragma unroll
    for (int i = 0; i < 4; ++i) { pv[i] = pk[k][d0 + i]; vb[i] = vv[k][h0 + i]; }
    #pragma unroll
    for (int i = 0; i < 4; ++i)
      #pragma unroll
      for (int j = 0; j < 4; ++j) s4[i][j] += pv[i] * vb[j];
  }
  const size_t base = (size_t)x * 4096;
  #pragma unroll
  for (int i = 0; i < 4; ++i)
    #pragma unroll
    for (int j = 0; j < 4; ++j)
      sT[base + (size_t)(h0 + j) * 64 + d0 + i] = f2bf(s4[i][j]);   // transposed store
  if (t < 64) {
    float zz = 0.f;
    for (int k = 0; k < 64; ++k) zz += pk[k][t];
    z[(size_t)x * 64 + t] = zz;
  }
}

// ---------------- qzinv[b,q,n] = 1/(phi_q . z + eps) ----------------
__global__ __launch_bounds__(256) void qz_k(
    const u16* __restrict__ phi_q, const float* __restrict__ z, float* __restrict__ qzinv)
{
  const int tid = blockIdx.x * 256 + threadIdx.x;  // 32*512*12
  const int n = tid % 12;
  const int bq = tid / 12;
  const int q = bq % 512, b = bq / 512;
  const u16* pq = phi_q + (size_t)(b * 512 + q) * 768 + n * 64;
  const float* zz = z + (size_t)(b * 12 + n) * 64;
  float acc = 0.f;
  #pragma unroll
  for (int c = 0; c < 64; c += 8) {
    u16x8 a = *(const u16x8*)&pq[c];
    #pragma unroll
    for (int i = 0; i < 8; ++i) acc += bf2f(a[i]) * zz[c + i];
  }
  qzinv[tid] = 1.0f / (acc + 1e-6f);
}

// ---------------- diagnostic fill (float out) ----------------
__global__ void tagfill_k(float* out, float val, int n) {
  int i = blockIdx.x * 256 + threadIdx.x;
  if (i < n) out[i] = val;
}

extern "C" void kernel_launch(void* const* d_in, const int* in_sizes, int n_in,
                              void* d_out, int out_size, void* d_ws, size_t ws_size,
                              hipStream_t stream) {
  (void)out_size;
  float* out = (float*)d_out;

  // --- input slot resolution + sanity ---
  int o;
  if (n_in >= 14 && in_sizes[3] == 1) o = 4;
  else if (n_in == 13) o = 3;
  else { tagfill_k<<<4, 256, 0, stream>>>(out, 77.0f, 1024); return; }
  if (in_sizes[0] != 12582912 || in_sizes[o + 0] != 32768 || in_sizes[o + 2] != 589824) {
    tagfill_k<<<4, 256, 0, stream>>>(out, 88.0f, 1024); return;
  }

  const float* query = (const float*)d_in[0];
  const float* key   = (const float*)d_in[1];
  const float* value = (const float*)d_in[2];
  const float* W_kds = (const float*)d_in[o + 0];
  const float* W_vds = (const float*)d_in[o + 1];
  const float* Wq   = (const float*)d_in[o + 2];
  const float* bq   = (const float*)d_in[o + 3];
  const float* Wk   = (const float*)d_in[o + 4];
  const float* bk   = (const float*)d_in[o + 5];
  const float* Wv   = (const float*)d_in[o + 6];
  const float* bv   = (const float*)d_in[o + 7];
  const float* Wout = (const float*)d_in[o + 8];
  const float* bout = (const float*)d_in[o + 9];

  // --- workspace layout (42,604,544 B) ---
  const size_t NEEDED = 42604544;
  if (ws_size < NEEDED) { tagfill_k<<<4, 256, 0, stream>>>(out, 123.0f, 1024); return; }
  char* base = (char*)d_ws;
  u16*   WT     = (u16*)(base);                                  // 4,718,592
  u16*   key_ds = (u16*)(base + 4718592);                        // 3,145,728
  u16*   val_ds = (u16*)(base + 7864320);                        // 3,145,728
  u16*   sT     = (u16*)(base + 4718592);                        // aliases key_ds (dead)
  float* zbuf   = (float*)(base + 7864320);                      // aliases val_ds (dead)
  float* qzinv  = (float*)(base + 7962624);                      // 786,432
  u16*   phi_k  = (u16*)(base + 11010048);                       // 3,145,728
  u16*   vals   = (u16*)(base + 14155776);                       // 3,145,728
  u16*   phi_q  = (u16*)(base + 17301504);                       // 25,165,824
  u16*   Wds_c  = (u16*)(base + 42467328);                       // 131,072
  u16*   bias_c = (u16*)(base + 42598400);                       // 6,144
  u16* a_v = phi_q;   // in-place: per-block read set == write set (disjoint n-col blocks)
  u16* WqT   = WT;
  u16* WkT   = WT + 768 * 768;
  u16* WvT   = WT + 2 * 768 * 768;
  u16* WoutT = WT + 3 * 768 * 768;
  u16* Wkds_c = Wds_c;
  u16* Wvds_c = Wds_c + 32768;
  u16* bq_c = bias_c, *bk_c = bias_c + 768, *bv_c = bias_c + 1536, *bout_c = bias_c + 2304;

  // --- canonicalize small fp32 inputs to bf16 ---
  convert_k<<<268, 256, 0, stream>>>(W_kds, W_vds, bq, bk, bv, bout, Wds_c, bias_c);
  transpose4_k<<<dim3(12, 12, 4), 256, 0, stream>>>(Wq, Wk, Wv, Wout, WT);

  // key_ds[b] = W_kds @ key[b]  (M=64,K=512,N=768, batch 32; B fp32, offsets now dtype-correct)
  gemm_k<64, 128, 32, 64, 32, true, 0, false, true, false><<<dim3(1, 6, 32), 256, 0, stream>>>(
      Wkds_c, 512, key, 768, key_ds, 768, nullptr, nullptr, 0, 512, 1,
      0, 0, (long long)512 * 768, 0, (long long)64 * 768, 0, 0, 0);
  gemm_k<64, 128, 32, 64, 32, true, 0, false, true, false><<<dim3(1, 6, 32), 256, 0, stream>>>(
      Wvds_c, 512, value, 768, val_ds, 768, nullptr, nullptr, 0, 512, 1,
      0, 0, (long long)512 * 768, 0, (long long)64 * 768, 0, 0, 0);

  // phi_q = elu(query @ Wq + bq) + 1   (A fp32)
  gemm_k<128, 128, 32, 64, 64, false, 1, true, false, false><<<dim3(128, 6, 1), 256, 0, stream>>>(
      query, 768, WqT, 768, phi_q, 768, bq_c, nullptr, 0, 768, 1,
      0, 0, 0, 0, 0, 0, 0, 0);
  // phi_k = elu(key_ds @ Wk + bk) + 1
  gemm_k<128, 128, 32, 64, 64, false, 1, false, false, false><<<dim3(16, 6, 1), 256, 0, stream>>>(
      key_ds, 768, WkT, 768, phi_k, 768, bk_c, nullptr, 0, 768, 1,
      0, 0, 0, 0, 0, 0, 0, 0);
  // vals = val_ds @ Wv + bv
  gemm_k<128, 128, 32, 64, 64, false, 0, false, false, false><<<dim3(16, 6, 1), 256, 0, stream>>>(
      val_ds, 768, WvT, 768, vals, 768, bv_c, nullptr, 0, 768, 1,
      0, 0, 0, 0, 0, 0, 0, 0);

  kv_state_k<<<dim3(384), 256, 0, stream>>>(phi_k, vals, sT, zbuf);
  qz_k<<<dim3(768), 256, 0, stream>>>(phi_q, zbuf, qzinv);

  // a_v = (phi_q @ s) * qzinv  (M=512,K=64,N=64, batch b*n), in-place into phi_q
  gemm_k<64, 64, 32, 32, 32, false, 2, false, false, false><<<dim3(8, 1, 384), 256, 0, stream>>>(
      phi_q, 768, sT, 64, a_v, 768, nullptr, qzinv, 12, 64, 12,
      (long long)512 * 768, 64, (long long)12 * 4096, 4096,
      (long long)512 * 768, 64, (long long)512 * 12, 1);

  // out = a_v @ Wout + bout   (C fp32)
  gemm_k<128, 128, 32, 64, 64, false, 0, false, false, true><<<dim3(128, 6, 1), 256, 0, stream>>>(
      a_v, 768, WoutT, 768, out, 768, bout_c, nullptr, 0, 768, 1,
      0, 0, 0, 0, 0, 0, 0, 0);
}

// Round 5
// 329.063 us; speedup vs baseline: 1.1095x; 1.1095x over previous
//
#include <hip/hip_runtime.h>

typedef unsigned short u16;
typedef u16 u16x8 __attribute__((ext_vector_type(8)));
typedef __bf16 bf16;
typedef bf16 bf16x8 __attribute__((ext_vector_type(8)));
typedef float f32x4 __attribute__((ext_vector_type(4)));

__device__ __forceinline__ float bf2f(u16 v) {
  union { unsigned u; float f; } x; x.u = ((unsigned)v) << 16; return x.f;
}
__device__ __forceinline__ u16 f2bf(float f) {
  union { float f; unsigned u; } x; x.f = f;
  unsigned u = x.u;
  u += 0x7fffu + ((u >> 16) & 1u);   // RNE
  return (u16)(u >> 16);
}

// async global->LDS, 16B per lane; LDS base must be wave-uniform (m104/m108)
#define GLDS16(g, l) __builtin_amdgcn_global_load_lds( \
    (const __attribute__((address_space(1))) unsigned int*)(const void*)(g), \
    (__attribute__((address_space(3))) unsigned int*)(void*)(l), 16, 0, 0)

// ---------------- convert small fp32 inputs to canonical bf16 ----------------
__global__ __launch_bounds__(256) void convert_k(
    const float* __restrict__ wk, const float* __restrict__ wv,
    const float* __restrict__ b0, const float* __restrict__ b1,
    const float* __restrict__ b2, const float* __restrict__ b3,
    u16* __restrict__ dstW, u16* __restrict__ dstB) {
  const int i = blockIdx.x * 256 + threadIdx.x;   // 268*256 = 68608
  if (i < 32768)      dstW[i] = f2bf(wk[i]);
  else if (i < 65536) dstW[i] = f2bf(wv[i - 32768]);
  else {
    int j = i - 65536, s = j / 768, si = j % 768;
    const float* src = (s == 0) ? b0 : (s == 1) ? b1 : (s == 2) ? b2 : b3;
    dstB[j] = f2bf(src[si]);
  }
}

// ---------------- bulk fp32 -> bf16 (query) ----------------
__global__ __launch_bounds__(256) void f32_to_bf16_k(
    const float* __restrict__ in, u16* __restrict__ out) {
  const int i = blockIdx.x * 256 + threadIdx.x;   // 6144*256 = 1572864, *8 = 12582912
  f32x4 a = *(const f32x4*)&in[(size_t)i * 8];
  f32x4 b = *(const f32x4*)&in[(size_t)i * 8 + 4];
  u16x8 w;
  #pragma unroll
  for (int j = 0; j < 4; ++j) { w[j] = f2bf(a[j]); w[4 + j] = f2bf(b[j]); }
  *(u16x8*)&out[(size_t)i * 8] = w;
}

// ---------------- 768x768 fp32 weight transpose -> bf16 (4 weights) ----------------
__global__ __launch_bounds__(256) void transpose4_k(
    const float* __restrict__ w0, const float* __restrict__ w1,
    const float* __restrict__ w2, const float* __restrict__ w3,
    u16* __restrict__ out) {
  const float* W = (blockIdx.z == 0) ? w0 : (blockIdx.z == 1) ? w1 : (blockIdx.z == 2) ? w2 : w3;
  u16* O = out + (size_t)blockIdx.z * 768 * 768;
  __shared__ u16 T[64][72];
  const int t = threadIdx.x;
  const int r0 = blockIdx.x * 64, c0 = blockIdx.y * 64;
  #pragma unroll
  for (int p = 0; p < 2; ++p) {
    int v = t + p * 256;
    int r = v / 8, c = (v % 8) * 8;
    f32x4 x0 = *(const f32x4*)&W[(size_t)(r0 + r) * 768 + c0 + c];
    f32x4 x1 = *(const f32x4*)&W[(size_t)(r0 + r) * 768 + c0 + c + 4];
    #pragma unroll
    for (int i = 0; i < 4; ++i) { T[r][c + i] = f2bf(x0[i]); T[r][c + 4 + i] = f2bf(x1[i]); }
  }
  __syncthreads();
  #pragma unroll
  for (int p = 0; p < 2; ++p) {
    int v = t + p * 256;
    int r = v / 8, c = (v % 8) * 8;
    u16x8 tv;
    #pragma unroll
    for (int i = 0; i < 8; ++i) tv[i] = T[c + i][r];
    *(u16x8*)&O[(size_t)(c0 + r) * 768 + r0 + c] = tv;
  }
}

// ---------------- m97-style GEMM: bf16 A[M,K] x Bt[N,K] -> C, global_load_lds ----------------
// BM=BN=128, BK=32, 4 waves of 64x64. ACT: 0 none, 1 elu+1. OF32: fp32 C.
template<int ACT, bool OF32>
__global__ __launch_bounds__(256) void gemm97_k(
    const u16* __restrict__ A, int lda,
    const u16* __restrict__ Bt, int ldb,
    void* __restrict__ Craw, int ldc,
    const u16* __restrict__ bias, int K)
{
  __shared__ u16 As[128 * 32];   // unpadded: global_load_lds needs contiguous lane order
  __shared__ u16 Bs[128 * 32];
  const int mt = blockIdx.x * 128, nt = blockIdx.y * 128;
  const int t = threadIdx.x, wave = t >> 6, lane = t & 63;
  const int wm = (wave >> 1) * 64, wn = (wave & 1) * 64;
  const int lrow = lane & 15, quad = lane >> 4;
  f32x4 acc[4][4] = {};

  for (int k0 = 0; k0 < K; k0 += 32) {
    __syncthreads();                       // protect LDS from previous iteration's readers
    #pragma unroll
    for (int p = 0; p < 2; ++p) {
      const int s = wave * 128 + p * 64 + lane;   // seg: 16B each; 512 segs per tile
      const int r = s >> 2, c = (s & 3) * 8;
      const int lb = (wave * 128 + p * 64) * 8;   // wave-uniform LDS base (u16 idx)
      GLDS16(&A[(size_t)(mt + r) * lda + k0 + c], &As[lb]);
      GLDS16(&Bt[(size_t)(nt + r) * ldb + k0 + c], &Bs[lb]);
    }
    __syncthreads();                       // drains vmcnt(0): loads complete

    bf16x8 av[4], bv[4];
    #pragma unroll
    for (int i = 0; i < 4; ++i) av[i] = *(const bf16x8*)&As[(wm + i * 16 + lrow) * 32 + quad * 8];
    #pragma unroll
    for (int j = 0; j < 4; ++j) bv[j] = *(const bf16x8*)&Bs[(wn + j * 16 + lrow) * 32 + quad * 8];
    #pragma unroll
    for (int i = 0; i < 4; ++i)
      #pragma unroll
      for (int j = 0; j < 4; ++j)
        acc[i][j] = __builtin_amdgcn_mfma_f32_16x16x32_bf16(av[i], bv[j], acc[i][j], 0, 0, 0);
  }

  #pragma unroll
  for (int i = 0; i < 4; ++i) {
    #pragma unroll
    for (int j = 0; j < 4; ++j) {
      const int col = nt + wn + j * 16 + lrow;
      const float badd = bias ? bf2f(bias[col]) : 0.0f;
      #pragma unroll
      for (int r = 0; r < 4; ++r) {
        const int row = mt + wm + i * 16 + quad * 4 + r;
        float v = acc[i][j][r] + badd;
        if constexpr (ACT == 1) v = v > 0.0f ? v + 1.0f : __expf(v);
        if constexpr (OF32) ((float*)Craw)[(size_t)row * ldc + col] = v;
        else                ((u16*)Craw)[(size_t)row * ldc + col] = f2bf(v);
      }
    }
  }
}

// ---------------- generic MFMA GEMM (padded LDS, per-operand dtype) ----------------
// ACT: 0 none, 1 elu+1, 3 = elu+1 iff bb==0 (batched phi_k/vals).
template<int BM, int BN, int BK, int WM, int WN, bool NN, int ACT,
         bool AF32, bool BF32, bool OF32>
__global__ __launch_bounds__(256) void gemm_k(
    const void* __restrict__ Araw, int lda,
    const void* __restrict__ Braw, int ldb,
    void* __restrict__ Craw, int ldc,
    const u16* __restrict__ bias,
    int K, int nDiv,
    long long offA_b, long long offA_n,
    long long offB_b, long long offB_n,
    long long offC_b, long long offC_n,
    long long offBias_b)
{
  constexpr int LDSK = BK + 8;
  __shared__ u16 As[BM][LDSK];
  __shared__ u16 Bs[BN][LDSK];

  const int z  = blockIdx.z;
  const int bb = z / nDiv, ni = z % nDiv;
  const long long dA = bb * offA_b + ni * offA_n;
  const long long dB = bb * offB_b + ni * offB_n;
  const long long dC = bb * offC_b + ni * offC_n;
  const u16*   A16 = AF32 ? nullptr : ((const u16*)Araw) + dA;
  const float* A32 = AF32 ? ((const float*)Araw) + dA : nullptr;
  const u16*   B16 = BF32 ? nullptr : ((const u16*)Braw) + dB;
  const float* B32 = BF32 ? ((const float*)Braw) + dB : nullptr;
  u16*   C16 = OF32 ? nullptr : ((u16*)Craw) + dC;
  float* C32 = OF32 ? ((float*)Craw) + dC : nullptr;
  if (bias) bias += bb * offBias_b;

  const int mt = blockIdx.x * BM;
  const int nt = blockIdx.y * BN;
  const int t = threadIdx.x;
  const int wave = t >> 6, lane = t & 63;
  constexpr int WAVES_N = BN / WN;
  const int wm = (wave / WAVES_N) * WM;
  const int wn = (wave % WAVES_N) * WN;
  constexpr int FM = WM / 16, FN = WN / 16;
  const int lrow = lane & 15, quad = lane >> 4;

  f32x4 acc[FM][FN] = {};

  for (int k0 = 0; k0 < K; k0 += BK) {
    __syncthreads();
    #pragma unroll
    for (int p = 0; p < (BM * BK / 8) / 256; ++p) {
      int v = t + p * 256;
      int r = v / (BK / 8);
      int c = (v % (BK / 8)) * 8;
      size_t idx = (size_t)(mt + r) * lda + k0 + c;
      if constexpr (!AF32) {
        *(u16x8*)&As[r][c] = *(const u16x8*)&A16[idx];
      } else {
        f32x4 x0 = *(const f32x4*)&A32[idx];
        f32x4 x1 = *(const f32x4*)&A32[idx + 4];
        u16x8 w;
        #pragma unroll
        for (int i = 0; i < 4; ++i) { w[i] = f2bf(x0[i]); w[4 + i] = f2bf(x1[i]); }
        *(u16x8*)&As[r][c] = w;
      }
    }
    if constexpr (!NN) {
      #pragma unroll
      for (int p = 0; p < (BN * BK / 8) / 256; ++p) {
        int v = t + p * 256;
        int r = v / (BK / 8);
        int c = (v % (BK / 8)) * 8;
        size_t idx = (size_t)(nt + r) * ldb + k0 + c;
        if constexpr (!BF32) {
          *(u16x8*)&Bs[r][c] = *(const u16x8*)&B16[idx];
        } else {
          f32x4 x0 = *(const f32x4*)&B32[idx];
          f32x4 x1 = *(const f32x4*)&B32[idx + 4];
          u16x8 w;
          #pragma unroll
          for (int i = 0; i < 4; ++i) { w[i] = f2bf(x0[i]); w[4 + i] = f2bf(x1[i]); }
          *(u16x8*)&Bs[r][c] = w;
        }
      }
    } else {
      static_assert(!NN || (BN == 128 && BK == 32), "NN staging is fixed-shape");
      int n  = t & 127;
      int kh = (t >> 7) * 16;
      u16x8 t0, t1;
      if constexpr (!BF32) {
        #pragma unroll
        for (int i = 0; i < 8; ++i) t0[i] = B16[(size_t)(k0 + kh + i) * ldb + nt + n];
        #pragma unroll
        for (int i = 0; i < 8; ++i) t1[i] = B16[(size_t)(k0 + kh + 8 + i) * ldb + nt + n];
      } else {
        #pragma unroll
        for (int i = 0; i < 8; ++i) t0[i] = f2bf(B32[(size_t)(k0 + kh + i) * ldb + nt + n]);
        #pragma unroll
        for (int i = 0; i < 8; ++i) t1[i] = f2bf(B32[(size_t)(k0 + kh + 8 + i) * ldb + nt + n]);
      }
      *(u16x8*)&Bs[n][kh]     = t0;
      *(u16x8*)&Bs[n][kh + 8] = t1;
    }
    __syncthreads();

    bf16x8 av[FM], bv[FN];
    #pragma unroll
    for (int i = 0; i < FM; ++i) av[i] = *(const bf16x8*)&As[wm + i * 16 + lrow][quad * 8];
    #pragma unroll
    for (int j = 0; j < FN; ++j) bv[j] = *(const bf16x8*)&Bs[wn + j * 16 + lrow][quad * 8];
    #pragma unroll
    for (int i = 0; i < FM; ++i)
      #pragma unroll
      for (int j = 0; j < FN; ++j)
        acc[i][j] = __builtin_amdgcn_mfma_f32_16x16x32_bf16(av[i], bv[j], acc[i][j], 0, 0, 0);
  }

  #pragma unroll
  for (int i = 0; i < FM; ++i) {
    #pragma unroll
    for (int j = 0; j < FN; ++j) {
      const int col = nt + wn + j * 16 + lrow;
      float badd = bias ? bf2f(bias[col]) : 0.0f;
      #pragma unroll
      for (int r = 0; r < 4; ++r) {
        const int row = mt + wm + i * 16 + quad * 4 + r;
        float v = acc[i][j][r] + badd;
        if constexpr (ACT == 1) v = v > 0.0f ? v + 1.0f : __expf(v);
        if constexpr (ACT == 3) { if (bb == 0) v = v > 0.0f ? v + 1.0f : __expf(v); }
        if constexpr (OF32) C32[(size_t)row * ldc + col] = v;
        else                C16[(size_t)row * ldc + col] = f2bf(v);
      }
    }
  }
}

// ---------------- per-(b,n) KV state: sT[h][d] = sum_k phi_k[k][d]*v[k][h]; z[d] ----------------
__global__ __launch_bounds__(256) void kv_state_k(
    const u16* __restrict__ phi_k, const u16* __restrict__ vals,
    u16* __restrict__ sT, float* __restrict__ z)
{
  __shared__ float pk[64][65];
  __shared__ float vv[64][65];
  const int x = blockIdx.x;          // b*12 + n
  const int b = x / 12, n = x % 12;
  const int t = threadIdx.x;
  const u16* pkg = phi_k + (size_t)b * 64 * 768 + n * 64;
  const u16* vvg = vals  + (size_t)b * 64 * 768 + n * 64;
  #pragma unroll
  for (int p = 0; p < 2; ++p) {
    int v = t + p * 256;
    int r = v / 8, c = (v % 8) * 8;
    u16x8 a  = *(const u16x8*)&pkg[(size_t)r * 768 + c];
    u16x8 bq = *(const u16x8*)&vvg[(size_t)r * 768 + c];
    #pragma unroll
    for (int i = 0; i < 8; ++i) { pk[r][c + i] = bf2f(a[i]); vv[r][c + i] = bf2f(bq[i]); }
  }
  __syncthreads();
  const int d0 = (t >> 4) * 4, h0 = (t & 15) * 4;
  float s4[4][4] = {};
  for (int k = 0; k < 64; ++k) {
    float pv[4], vb[4];
    #pragma unroll
    for (int i = 0; i < 4; ++i) { pv[i] = pk[k][d0 + i]; vb[i] = vv[k][h0 + i]; }
    #pragma unroll
    for (int i = 0; i < 4; ++i)
      #pragma unroll
      for (int j = 0; j < 4; ++j) s4[i][j] += pv[i] * vb[j];
  }
  const size_t base = (size_t)x * 4096;
  #pragma unroll
  for (int i = 0; i < 4; ++i)
    #pragma unroll
    for (int j = 0; j < 4; ++j)
      sT[base + (size_t)(h0 + j) * 64 + d0 + i] = f2bf(s4[i][j]);
  if (t < 64) {
    float zz = 0.f;
    for (int k = 0; k < 64; ++k) zz += pk[k][t];
    z[(size_t)x * 64 + t] = zz;
  }
}

// ---------------- a_v = (phi_q @ s) / (phi_q . z + eps), fused qz, in-place ----------------
// grid (8, 384): x = q-tile (64 rows), y = b*12+n. K=64 (one head slice).
__global__ __launch_bounds__(256) void attn_av_k(
    u16* __restrict__ phi_q,          // [32,512,768] in/out
    const u16* __restrict__ sT,       // [384,64,64] (row h, col d)
    const float* __restrict__ zbuf)   // [384,64]
{
  __shared__ u16 As[64 * 72];
  __shared__ u16 Bs[64 * 72];
  __shared__ float zv[64];
  __shared__ float zpart[4][64];
  __shared__ float zq[64];
  const int x = blockIdx.x, y = blockIdx.y;
  const int b = y / 12, n = y % 12;
  const int t = threadIdx.x;
  u16* Abase = phi_q + (size_t)b * 512 * 768 + (size_t)x * 64 * 768 + n * 64;
  const u16* Bbase = sT + (size_t)y * 4096;
  if (t < 64) zv[t] = zbuf[(size_t)y * 64 + t];
  #pragma unroll
  for (int p = 0; p < 2; ++p) {
    int v = t + p * 256;
    int r = v >> 3, c = (v & 7) * 8;
    *(u16x8*)&As[r * 72 + c] = *(const u16x8*)&Abase[(size_t)r * 768 + c];
    *(u16x8*)&Bs[r * 72 + c] = *(const u16x8*)&Bbase[r * 64 + c];
  }
  __syncthreads();
  {
    int r = t & 63, seg = t >> 6;
    float s = 0.f;
    #pragma unroll
    for (int j = 0; j < 16; ++j) s += bf2f(As[r * 72 + seg * 16 + j]) * zv[seg * 16 + j];
    zpart[seg][r] = s;
  }
  __syncthreads();
  if (t < 64) {
    float s = zpart[0][t] + zpart[1][t] + zpart[2][t] + zpart[3][t];
    zq[t] = 1.0f / (s + 1e-6f);
  }
  const int wave = t >> 6, lane = t & 63;
  const int wm = (wave >> 1) * 32, wn = (wave & 1) * 32;
  const int lrow = lane & 15, quad = lane >> 4;
  f32x4 acc[2][2] = {};
  #pragma unroll
  for (int c = 0; c < 2; ++c) {
    bf16x8 av[2], bv[2];
    #pragma unroll
    for (int i = 0; i < 2; ++i) av[i] = *(const bf16x8*)&As[(wm + i * 16 + lrow) * 72 + c * 32 + quad * 8];
    #pragma unroll
    for (int j = 0; j < 2; ++j) bv[j] = *(const bf16x8*)&Bs[(wn + j * 16 + lrow) * 72 + c * 32 + quad * 8];
    #pragma unroll
    for (int i = 0; i < 2; ++i)
      #pragma unroll
      for (int j = 0; j < 2; ++j)
        acc[i][j] = __builtin_amdgcn_mfma_f32_16x16x32_bf16(av[i], bv[j], acc[i][j], 0, 0, 0);
  }
  __syncthreads();   // zq ready; all staging reads done -> in-place write safe
  #pragma unroll
  for (int i = 0; i < 2; ++i)
    #pragma unroll
    for (int j = 0; j < 2; ++j) {
      const int col = wn + j * 16 + lrow;
      #pragma unroll
      for (int r = 0; r < 4; ++r) {
        const int row = wm + i * 16 + quad * 4 + r;
        Abase[(size_t)row * 768 + col] = f2bf(acc[i][j][r] * zq[row]);
      }
    }
}

// ---------------- diagnostic fill ----------------
__global__ void tagfill_k(float* out, float val, int n) {
  int i = blockIdx.x * 256 + threadIdx.x;
  if (i < n) out[i] = val;
}

extern "C" void kernel_launch(void* const* d_in, const int* in_sizes, int n_in,
                              void* d_out, int out_size, void* d_ws, size_t ws_size,
                              hipStream_t stream) {
  (void)out_size;
  float* out = (float*)d_out;

  int o;
  if (n_in >= 14 && in_sizes[3] == 1) o = 4;
  else if (n_in == 13) o = 3;
  else { tagfill_k<<<4, 256, 0, stream>>>(out, 77.0f, 1024); return; }
  if (in_sizes[0] != 12582912 || in_sizes[o + 0] != 32768 || in_sizes[o + 2] != 589824) {
    tagfill_k<<<4, 256, 0, stream>>>(out, 88.0f, 1024); return;
  }

  const float* query = (const float*)d_in[0];
  const float* key   = (const float*)d_in[1];
  const float* value = (const float*)d_in[2];
  const float* W_kds = (const float*)d_in[o + 0];
  const float* W_vds = (const float*)d_in[o + 1];
  const float* Wq   = (const float*)d_in[o + 2];
  const float* bq   = (const float*)d_in[o + 3];
  const float* Wk   = (const float*)d_in[o + 4];
  const float* bk   = (const float*)d_in[o + 5];
  const float* Wv   = (const float*)d_in[o + 6];
  const float* bv   = (const float*)d_in[o + 7];
  const float* Wout = (const float*)d_in[o + 8];
  const float* bout = (const float*)d_in[o + 9];

  const size_t NEED_SMALL = 42604544;
  const size_t NEED_BIG   = 55187456;
  if (ws_size < NEED_SMALL) { tagfill_k<<<4, 256, 0, stream>>>(out, 123.0f, 1024); return; }
  const bool big = (ws_size >= NEED_BIG);

  char* base = (char*)d_ws;
  u16 *WT, *q_bf = nullptr, *key_ds, *val_ds, *phi_k, *vals, *phi_q, *sT, *Wds_c, *bias_c;
  float* zbuf;
  WT = (u16*)base;
  if (big) {
    // region B (25.17MB): q_bf first; after phi_q-gemm consumes it, reused by
    // key_ds/val_ds/phi_k/vals and then sT/zbuf.
    char* B = base + 4718592;
    q_bf   = (u16*)B;
    key_ds = (u16*)B;
    val_ds = (u16*)(B + 3145728);
    phi_k  = (u16*)(B + 6291456);
    vals   = (u16*)(B + 9437184);
    sT     = (u16*)B;                      // over key_ds (dead)
    zbuf   = (float*)(B + 3145728);        // over val_ds (dead)
    phi_q  = (u16*)(base + 29884416);
    Wds_c  = (u16*)(base + 55050240);
    bias_c = (u16*)(base + 55181312);
  } else {
    key_ds = (u16*)(base + 4718592);
    val_ds = (u16*)(base + 7864320);
    sT     = (u16*)(base + 4718592);
    zbuf   = (float*)(base + 7864320);
    phi_k  = (u16*)(base + 11010048);
    vals   = (u16*)(base + 14155776);
    phi_q  = (u16*)(base + 17301504);
    Wds_c  = (u16*)(base + 42467328);
    bias_c = (u16*)(base + 42598400);
  }
  u16* a_v = phi_q;
  u16* WqT   = WT;
  u16* WkT   = WT + 768 * 768;
  u16* WvT   = WT + 2 * 768 * 768;
  u16* WoutT = WT + 3 * 768 * 768;
  u16* Wkds_c = Wds_c;
  u16* Wvds_c = Wds_c + 32768;
  u16* bq_c = bias_c, *bk_c = bias_c + 768, *bv_c = bias_c + 1536, *bout_c = bias_c + 2304;

  convert_k<<<268, 256, 0, stream>>>(W_kds, W_vds, bq, bk, bv, bout, Wds_c, bias_c);
  transpose4_k<<<dim3(12, 12, 4), 256, 0, stream>>>(Wq, Wk, Wv, Wout, WT);

  // phi_q = elu(query @ Wq + bq) + 1 — m97 path (via bf16 query) when ws allows
  if (big) {
    f32_to_bf16_k<<<6144, 256, 0, stream>>>(query, q_bf);
    gemm97_k<1, false><<<dim3(128, 6), 256, 0, stream>>>(
        q_bf, 768, WqT, 768, phi_q, 768, bq_c, 768);
  } else {
    gemm_k<128, 128, 32, 64, 64, false, 1, true, false, false><<<dim3(128, 6, 1), 256, 0, stream>>>(
        query, 768, WqT, 768, phi_q, 768, bq_c, 768, 1, 0, 0, 0, 0, 0, 0, 0);
  }

  // downsample: key_ds[b] = W_kds @ key[b], val_ds[b] = W_vds @ value[b]
  gemm_k<64, 128, 32, 64, 32, true, 0, false, true, false><<<dim3(1, 6, 32), 256, 0, stream>>>(
      Wkds_c, 512, key, 768, key_ds, 768, nullptr, 512, 1,
      0, 0, (long long)512 * 768, 0, (long long)64 * 768, 0, 0);
  gemm_k<64, 128, 32, 64, 32, true, 0, false, true, false><<<dim3(1, 6, 32), 256, 0, stream>>>(
      Wvds_c, 512, value, 768, val_ds, 768, nullptr, 512, 1,
      0, 0, (long long)512 * 768, 0, (long long)64 * 768, 0, 0);

  // batched: z=0 -> phi_k = elu(key_ds@Wk+bk)+1 ; z=1 -> vals = val_ds@Wv+bv
  gemm_k<64, 64, 32, 32, 32, false, 3, false, false, false><<<dim3(32, 12, 2), 256, 0, stream>>>(
      key_ds, 768, WkT, 768, phi_k, 768, bk_c, 768, 1,
      1572864, 0, 589824, 0, 1572864, 0, 768);

  kv_state_k<<<dim3(384), 256, 0, stream>>>(phi_k, vals, sT, zbuf);

  // a_v = (phi_q @ s) * 1/(phi_q.z+eps), fused qz, in-place
  attn_av_k<<<dim3(8, 384), 256, 0, stream>>>(phi_q, sT, zbuf);

  // out = a_v @ Wout + bout (fp32 C) — m97 path
  gemm97_k<0, true><<<dim3(128, 6), 256, 0, stream>>>(
      a_v, 768, WoutT, 768, out, 768, bout_c, 768);
}

// Round 6
// 313.305 us; speedup vs baseline: 1.1653x; 1.0503x over previous
//
#include <hip/hip_runtime.h>

typedef unsigned short u16;
typedef u16 u16x8 __attribute__((ext_vector_type(8)));
typedef __bf16 bf16;
typedef bf16 bf16x8 __attribute__((ext_vector_type(8)));
typedef float f32x4 __attribute__((ext_vector_type(4)));

__device__ __forceinline__ float bf2f(u16 v) {
  union { unsigned u; float f; } x; x.u = ((unsigned)v) << 16; return x.f;
}
__device__ __forceinline__ u16 f2bf(float f) {
  union { float f; unsigned u; } x; x.f = f;
  unsigned u = x.u;
  u += 0x7fffu + ((u >> 16) & 1u);   // RNE
  return (u16)(u >> 16);
}

// async global->LDS, 16B per lane; LDS base must be wave-uniform (m104/m108)
#define GLDS16(g, l) __builtin_amdgcn_global_load_lds( \
    (const __attribute__((address_space(1))) unsigned int*)(const void*)(g), \
    (__attribute__((address_space(3))) unsigned int*)(void*)(l), 16, 0, 0)

// ---------------- fused prep: 4 weight transposes + query cvt + small cvts ----------------
// grid 6988: [0,576) transpose4; [576,6720) query fp32->bf16; [6720,6988) small converts
__global__ __launch_bounds__(256) void prep_k(
    const float* __restrict__ Wq, const float* __restrict__ Wk,
    const float* __restrict__ Wv, const float* __restrict__ Wout,
    const float* __restrict__ query,
    const float* __restrict__ wkds, const float* __restrict__ wvds,
    const float* __restrict__ b0, const float* __restrict__ b1,
    const float* __restrict__ b2, const float* __restrict__ b3,
    u16* __restrict__ WT, u16* __restrict__ q_bf,
    u16* __restrict__ dstW, u16* __restrict__ dstB)
{
  __shared__ u16 T[64][72];
  const int blk = blockIdx.x;
  const int t = threadIdx.x;
  if (blk < 576) {
    const int bz = blk / 144, rr = blk % 144;
    const int r0 = (rr / 12) * 64, c0 = (rr % 12) * 64;
    const float* W = (bz == 0) ? Wq : (bz == 1) ? Wk : (bz == 2) ? Wv : Wout;
    u16* O = WT + (size_t)bz * 768 * 768;
    #pragma unroll
    for (int p = 0; p < 2; ++p) {
      int v = t + p * 256;
      int r = v / 8, c = (v % 8) * 8;
      f32x4 x0 = *(const f32x4*)&W[(size_t)(r0 + r) * 768 + c0 + c];
      f32x4 x1 = *(const f32x4*)&W[(size_t)(r0 + r) * 768 + c0 + c + 4];
      #pragma unroll
      for (int i = 0; i < 4; ++i) { T[r][c + i] = f2bf(x0[i]); T[r][c + 4 + i] = f2bf(x1[i]); }
    }
    __syncthreads();
    #pragma unroll
    for (int p = 0; p < 2; ++p) {
      int v = t + p * 256;
      int r = v / 8, c = (v % 8) * 8;
      u16x8 tv;
      #pragma unroll
      for (int i = 0; i < 8; ++i) tv[i] = T[c + i][r];
      *(u16x8*)&O[(size_t)(c0 + r) * 768 + r0 + c] = tv;
    }
  } else if (blk < 6720) {
    const size_t i = (size_t)(blk - 576) * 256 + t;   // 6144*256 slots, *8 = 12582912
    f32x4 a = *(const f32x4*)&query[i * 8];
    f32x4 b = *(const f32x4*)&query[i * 8 + 4];
    u16x8 w;
    #pragma unroll
    for (int j = 0; j < 4; ++j) { w[j] = f2bf(a[j]); w[4 + j] = f2bf(b[j]); }
    *(u16x8*)&q_bf[i * 8] = w;
  } else {
    const int i = (blk - 6720) * 256 + t;   // 268*256 = 68608 = 65536 + 3072
    if (i < 32768)      dstW[i] = f2bf(wkds[i]);
    else if (i < 65536) dstW[i] = f2bf(wvds[i - 32768]);
    else {
      int j = i - 65536, s = j / 768, si = j % 768;
      const float* src = (s == 0) ? b0 : (s == 1) ? b1 : (s == 2) ? b2 : b3;
      dstB[j] = f2bf(src[si]);
    }
  }
}

// ---------------- merged downsample: {key_ds,val_ds}[b] = W_{k,v}ds @ {key,value}[b] ----------
// grid (6, 64): y = pair*32 + b; x = 128-wide n-tile. M=64, N=128, K=512.
__global__ __launch_bounds__(256) void ds_k(
    const u16* __restrict__ Wds,      // bf16 [2][64][512]
    const float* __restrict__ key, const float* __restrict__ value,
    u16* __restrict__ key_ds)         // [2][32][64][768] (key_ds ++ val_ds contiguous)
{
  __shared__ u16 As[64][40];   // pad->bank stride 20: 2-way max (free, m136)
  __shared__ u16 Bs[128][36];  // pad->bank stride 18: 2-way max
  const int pair = blockIdx.y >> 5, b = blockIdx.y & 31;
  const float* src = (pair ? value : key) + (size_t)b * 512 * 768;
  const u16* W = Wds + pair * 32768;
  u16* dst = key_ds + (size_t)pair * 1572864 + (size_t)b * 49152;
  const int nt = blockIdx.x * 128;
  const int t = threadIdx.x, wave = t >> 6, lane = t & 63;
  const int wm = (wave >> 1) * 32, wn = (wave & 1) * 64;
  const int lrow = lane & 15, quad = lane >> 4;
  const int kk = t >> 5, n4 = (t & 31) * 4;

  f32x4 acc[2][4] = {};
  for (int k0 = 0; k0 < 512; k0 += 32) {
    __syncthreads();
    { // A tile 64x32 bf16, one u16x8 per thread
      int r = t >> 2, c = (t & 3) * 8;
      *(u16x8*)&As[r][c] = *(const u16x8*)&W[(size_t)r * 512 + k0 + c];
    }
    // B tile: transpose-stage fp32 key[k0+k][nt+n] -> Bs[n][k], vector f32x4 along n
    #pragma unroll
    for (int p = 0; p < 4; ++p) {
      int k = kk + p * 8;
      f32x4 x = *(const f32x4*)&src[(size_t)(k0 + k) * 768 + nt + n4];
      #pragma unroll
      for (int i = 0; i < 4; ++i) Bs[n4 + i][k] = f2bf(x[i]);
    }
    __syncthreads();
    bf16x8 av[2], bv[4];
    #pragma unroll
    for (int i = 0; i < 2; ++i) av[i] = *(const bf16x8*)&As[wm + i * 16 + lrow][quad * 8];
    #pragma unroll
    for (int j = 0; j < 4; ++j) bv[j] = *(const bf16x8*)&Bs[wn + j * 16 + lrow][quad * 8];
    #pragma unroll
    for (int i = 0; i < 2; ++i)
      #pragma unroll
      for (int j = 0; j < 4; ++j)
        acc[i][j] = __builtin_amdgcn_mfma_f32_16x16x32_bf16(av[i], bv[j], acc[i][j], 0, 0, 0);
  }
  #pragma unroll
  for (int i = 0; i < 2; ++i)
    #pragma unroll
    for (int j = 0; j < 4; ++j) {
      const int col = nt + wn + j * 16 + lrow;
      #pragma unroll
      for (int r = 0; r < 4; ++r) {
        const int row = wm + i * 16 + quad * 4 + r;
        dst[(size_t)row * 768 + col] = f2bf(acc[i][j][r]);
      }
    }
}

// ---------------- m97-style GEMM: bf16 A[M,K] x Bt[N,K] -> C, global_load_lds ----------------
template<int ACT, bool OF32>
__global__ __launch_bounds__(256) void gemm97_k(
    const u16* __restrict__ A, int lda,
    const u16* __restrict__ Bt, int ldb,
    void* __restrict__ Craw, int ldc,
    const u16* __restrict__ bias, int K)
{
  __shared__ u16 As[128 * 32];   // unpadded: GLDS needs contiguous lane order
  __shared__ u16 Bs[128 * 32];
  const int mt = blockIdx.x * 128, nt = blockIdx.y * 128;
  const int t = threadIdx.x, wave = t >> 6, lane = t & 63;
  const int wm = (wave >> 1) * 64, wn = (wave & 1) * 64;
  const int lrow = lane & 15, quad = lane >> 4;
  f32x4 acc[4][4] = {};

  for (int k0 = 0; k0 < K; k0 += 32) {
    __syncthreads();
    #pragma unroll
    for (int p = 0; p < 2; ++p) {
      const int s = wave * 128 + p * 64 + lane;
      const int r = s >> 2, c = (s & 3) * 8;
      const int lb = (wave * 128 + p * 64) * 8;
      GLDS16(&A[(size_t)(mt + r) * lda + k0 + c], &As[lb]);
      GLDS16(&Bt[(size_t)(nt + r) * ldb + k0 + c], &Bs[lb]);
    }
    __syncthreads();

    bf16x8 av[4], bv[4];
    #pragma unroll
    for (int i = 0; i < 4; ++i) av[i] = *(const bf16x8*)&As[(wm + i * 16 + lrow) * 32 + quad * 8];
    #pragma unroll
    for (int j = 0; j < 4; ++j) bv[j] = *(const bf16x8*)&Bs[(wn + j * 16 + lrow) * 32 + quad * 8];
    #pragma unroll
    for (int i = 0; i < 4; ++i)
      #pragma unroll
      for (int j = 0; j < 4; ++j)
        acc[i][j] = __builtin_amdgcn_mfma_f32_16x16x32_bf16(av[i], bv[j], acc[i][j], 0, 0, 0);
  }

  #pragma unroll
  for (int i = 0; i < 4; ++i) {
    #pragma unroll
    for (int j = 0; j < 4; ++j) {
      const int col = nt + wn + j * 16 + lrow;
      const float badd = bias ? bf2f(bias[col]) : 0.0f;
      #pragma unroll
      for (int r = 0; r < 4; ++r) {
        const int row = mt + wm + i * 16 + quad * 4 + r;
        float v = acc[i][j][r] + badd;
        if constexpr (ACT == 1) v = v > 0.0f ? v + 1.0f : __expf(v);
        if constexpr (OF32) ((float*)Craw)[(size_t)row * ldc + col] = v;
        else                ((u16*)Craw)[(size_t)row * ldc + col] = f2bf(v);
      }
    }
  }
}

// ---------------- batched bf16 GEMM for phi_k / vals (ACT3: elu+1 iff bb==0) ----------------
template<int BM, int BN, int BK, int WM, int WN>
__global__ __launch_bounds__(256) void gemmkv_k(
    const u16* __restrict__ A, int lda,
    const u16* __restrict__ B, int ldb,
    u16* __restrict__ C, int ldc,
    const u16* __restrict__ bias,
    int K,
    long long offA_b, long long offB_b, long long offC_b, long long offBias_b)
{
  constexpr int LDSK = BK + 8;
  __shared__ u16 As[BM][LDSK];
  __shared__ u16 Bs[BN][LDSK];
  const int bb = blockIdx.z;
  A += bb * offA_b; B += bb * offB_b; C += bb * offC_b; bias += bb * offBias_b;
  const int mt = blockIdx.x * BM;
  const int nt = blockIdx.y * BN;
  const int t = threadIdx.x;
  const int wave = t >> 6, lane = t & 63;
  constexpr int WAVES_N = BN / WN;
  const int wm = (wave / WAVES_N) * WM;
  const int wn = (wave % WAVES_N) * WN;
  constexpr int FM = WM / 16, FN = WN / 16;
  const int lrow = lane & 15, quad = lane >> 4;
  f32x4 acc[FM][FN] = {};

  for (int k0 = 0; k0 < K; k0 += BK) {
    __syncthreads();
    #pragma unroll
    for (int p = 0; p < (BM * BK / 8) / 256; ++p) {
      int v = t + p * 256;
      int r = v / (BK / 8), c = (v % (BK / 8)) * 8;
      *(u16x8*)&As[r][c] = *(const u16x8*)&A[(size_t)(mt + r) * lda + k0 + c];
    }
    #pragma unroll
    for (int p = 0; p < (BN * BK / 8) / 256; ++p) {
      int v = t + p * 256;
      int r = v / (BK / 8), c = (v % (BK / 8)) * 8;
      *(u16x8*)&Bs[r][c] = *(const u16x8*)&B[(size_t)(nt + r) * ldb + k0 + c];
    }
    __syncthreads();
    bf16x8 av[FM], bv[FN];
    #pragma unroll
    for (int i = 0; i < FM; ++i) av[i] = *(const bf16x8*)&As[wm + i * 16 + lrow][quad * 8];
    #pragma unroll
    for (int j = 0; j < FN; ++j) bv[j] = *(const bf16x8*)&Bs[wn + j * 16 + lrow][quad * 8];
    #pragma unroll
    for (int i = 0; i < FM; ++i)
      #pragma unroll
      for (int j = 0; j < FN; ++j)
        acc[i][j] = __builtin_amdgcn_mfma_f32_16x16x32_bf16(av[i], bv[j], acc[i][j], 0, 0, 0);
  }
  #pragma unroll
  for (int i = 0; i < FM; ++i)
    #pragma unroll
    for (int j = 0; j < FN; ++j) {
      const int col = nt + wn + j * 16 + lrow;
      const float badd = bf2f(bias[col]);
      #pragma unroll
      for (int r = 0; r < 4; ++r) {
        const int row = mt + wm + i * 16 + quad * 4 + r;
        float v = acc[i][j][r] + badd;
        if (bb == 0) v = v > 0.0f ? v + 1.0f : __expf(v);
        C[(size_t)row * ldc + col] = f2bf(v);
      }
    }
}

// ---------------- per-(b,n) KV state: sT[h][d] = sum_k phi_k[k][d]*v[k][h]; z[d] ----------------
__global__ __launch_bounds__(256) void kv_state_k(
    const u16* __restrict__ phi_k, const u16* __restrict__ vals,
    u16* __restrict__ sT, float* __restrict__ z)
{
  __shared__ float pk[64][65];
  __shared__ float vv[64][65];
  const int x = blockIdx.x;          // b*12 + n
  const int b = x / 12, n = x % 12;
  const int t = threadIdx.x;
  const u16* pkg = phi_k + (size_t)b * 64 * 768 + n * 64;
  const u16* vvg = vals  + (size_t)b * 64 * 768 + n * 64;
  #pragma unroll
  for (int p = 0; p < 2; ++p) {
    int v = t + p * 256;
    int r = v / 8, c = (v % 8) * 8;
    u16x8 a  = *(const u16x8*)&pkg[(size_t)r * 768 + c];
    u16x8 bq = *(const u16x8*)&vvg[(size_t)r * 768 + c];
    #pragma unroll
    for (int i = 0; i < 8; ++i) { pk[r][c + i] = bf2f(a[i]); vv[r][c + i] = bf2f(bq[i]); }
  }
  __syncthreads();
  const int d0 = (t >> 4) * 4, h0 = (t & 15) * 4;
  float s4[4][4] = {};
  for (int k = 0; k < 64; ++k) {
    float pv[4], vb[4];
    #pragma unroll
    for (int i = 0; i < 4; ++i) { pv[i] = pk[k][d0 + i]; vb[i] = vv[k][h0 + i]; }
    #pragma unroll
    for (int i = 0; i < 4; ++i)
      #pragma unroll
      for (int j = 0; j < 4; ++j) s4[i][j] += pv[i] * vb[j];
  }
  const size_t base = (size_t)x * 4096;
  #pragma unroll
  for (int i = 0; i < 4; ++i)
    #pragma unroll
    for (int j = 0; j < 4; ++j)
      sT[base + (size_t)(h0 + j) * 64 + d0 + i] = f2bf(s4[i][j]);
  if (t < 64) {
    float zz = 0.f;
    for (int k = 0; k < 64; ++k) zz += pk[k][t];
    z[(size_t)x * 64 + t] = zz;
  }
}

// ---------------- a_v = (phi_q @ s) / (phi_q . z + eps), fused qz, in-place ----------------
__global__ __launch_bounds__(256) void attn_av_k(
    u16* __restrict__ phi_q, const u16* __restrict__ sT, const float* __restrict__ zbuf)
{
  __shared__ u16 As[64 * 72];
  __shared__ u16 Bs[64 * 72];
  __shared__ float zv[64];
  __shared__ float zpart[4][64];
  __shared__ float zq[64];
  const int x = blockIdx.x, y = blockIdx.y;
  const int b = y / 12, n = y % 12;
  const int t = threadIdx.x;
  u16* Abase = phi_q + (size_t)b * 512 * 768 + (size_t)x * 64 * 768 + n * 64;
  const u16* Bbase = sT + (size_t)y * 4096;
  if (t < 64) zv[t] = zbuf[(size_t)y * 64 + t];
  #pragma unroll
  for (int p = 0; p < 2; ++p) {
    int v = t + p * 256;
    int r = v >> 3, c = (v & 7) * 8;
    *(u16x8*)&As[r * 72 + c] = *(const u16x8*)&Abase[(size_t)r * 768 + c];
    *(u16x8*)&Bs[r * 72 + c] = *(const u16x8*)&Bbase[r * 64 + c];
  }
  __syncthreads();
  {
    int r = t & 63, seg = t >> 6;
    float s = 0.f;
    #pragma unroll
    for (int j = 0; j < 16; ++j) s += bf2f(As[r * 72 + seg * 16 + j]) * zv[seg * 16 + j];
    zpart[seg][r] = s;
  }
  __syncthreads();
  if (t < 64) {
    float s = zpart[0][t] + zpart[1][t] + zpart[2][t] + zpart[3][t];
    zq[t] = 1.0f / (s + 1e-6f);
  }
  const int wave = t >> 6, lane = t & 63;
  const int wm = (wave >> 1) * 32, wn = (wave & 1) * 32;
  const int lrow = lane & 15, quad = lane >> 4;
  f32x4 acc[2][2] = {};
  #pragma unroll
  for (int c = 0; c < 2; ++c) {
    bf16x8 av[2], bv[2];
    #pragma unroll
    for (int i = 0; i < 2; ++i) av[i] = *(const bf16x8*)&As[(wm + i * 16 + lrow) * 72 + c * 32 + quad * 8];
    #pragma unroll
    for (int j = 0; j < 2; ++j) bv[j] = *(const bf16x8*)&Bs[(wn + j * 16 + lrow) * 72 + c * 32 + quad * 8];
    #pragma unroll
    for (int i = 0; i < 2; ++i)
      #pragma unroll
      for (int j = 0; j < 2; ++j)
        acc[i][j] = __builtin_amdgcn_mfma_f32_16x16x32_bf16(av[i], bv[j], acc[i][j], 0, 0, 0);
  }
  __syncthreads();
  #pragma unroll
  for (int i = 0; i < 2; ++i)
    #pragma unroll
    for (int j = 0; j < 2; ++j) {
      const int col = wn + j * 16 + lrow;
      #pragma unroll
      for (int r = 0; r < 4; ++r) {
        const int row = wm + i * 16 + quad * 4 + r;
        Abase[(size_t)row * 768 + col] = f2bf(acc[i][j][r] * zq[row]);
      }
    }
}

__global__ void tagfill_k(float* out, float val, int n) {
  int i = blockIdx.x * 256 + threadIdx.x;
  if (i < n) out[i] = val;
}

extern "C" void kernel_launch(void* const* d_in, const int* in_sizes, int n_in,
                              void* d_out, int out_size, void* d_ws, size_t ws_size,
                              hipStream_t stream) {
  (void)out_size;
  float* out = (float*)d_out;

  int o;
  if (n_in >= 14 && in_sizes[3] == 1) o = 4;
  else if (n_in == 13) o = 3;
  else { tagfill_k<<<4, 256, 0, stream>>>(out, 77.0f, 1024); return; }
  if (in_sizes[0] != 12582912 || in_sizes[o + 0] != 32768 || in_sizes[o + 2] != 589824) {
    tagfill_k<<<4, 256, 0, stream>>>(out, 88.0f, 1024); return;
  }

  const float* query = (const float*)d_in[0];
  const float* key   = (const float*)d_in[1];
  const float* value = (const float*)d_in[2];
  const float* W_kds = (const float*)d_in[o + 0];
  const float* W_vds = (const float*)d_in[o + 1];
  const float* Wq   = (const float*)d_in[o + 2];
  const float* bq   = (const float*)d_in[o + 3];
  const float* Wk   = (const float*)d_in[o + 4];
  const float* bk   = (const float*)d_in[o + 5];
  const float* Wv   = (const float*)d_in[o + 6];
  const float* bv   = (const float*)d_in[o + 7];
  const float* Wout = (const float*)d_in[o + 8];
  const float* bout = (const float*)d_in[o + 9];

  const size_t NEED = 55187456;     // measured ws = 256 MiB (round-5 fills), ample
  if (ws_size < NEED) { tagfill_k<<<4, 256, 0, stream>>>(out, 123.0f, 1024); return; }

  char* base = (char*)d_ws;
  u16*   WT     = (u16*)base;                         // 4,718,592
  char*  Breg   = base + 4718592;                     // 25,165,824 region
  u16*   q_bf   = (u16*)Breg;                         // dies after phi_q GEMM
  u16*   key_ds = (u16*)Breg;                         // then key_ds ++ val_ds (6.3MB)
  u16*   sT     = (u16*)Breg;                         // then sT (over key_ds, dead)
  float* zbuf   = (float*)(Breg + 3145728);           // over val_ds (dead)
  u16*   phi_k  = (u16*)(Breg + 6291456);             // 3,145,728
  u16*   vals   = (u16*)(Breg + 9437184);             // 3,145,728
  u16*   phi_q  = (u16*)(base + 29884416);            // 25,165,824
  u16*   Wds_c  = (u16*)(base + 55050240);            // 131,072
  u16*   bias_c = (u16*)(base + 55181312);            // 6,144
  u16* a_v = phi_q;
  u16* WqT   = WT;
  u16* WkT   = WT + 768 * 768;
  u16* WoutT = WT + 3 * 768 * 768;
  u16* bq_c = bias_c, *bk_c = bias_c + 768, *bout_c = bias_c + 2304;

  // 1. fused prep
  prep_k<<<6988, 256, 0, stream>>>(Wq, Wk, Wv, Wout, query, W_kds, W_vds,
                                   bq, bk, bv, bout, WT, q_bf, Wds_c, bias_c);

  // 2. phi_q = elu(q_bf @ Wq + bq) + 1
  gemm97_k<1, false><<<dim3(128, 6), 256, 0, stream>>>(
      q_bf, 768, WqT, 768, phi_q, 768, bq_c, 768);

  // 3. merged downsample (overwrites q_bf region — stream-ordered after step 2)
  ds_k<<<dim3(6, 64), 256, 0, stream>>>(Wds_c, key, value, key_ds);

  // 4. batched: bb=0 -> phi_k = elu(key_ds@Wk+bk)+1 ; bb=1 -> vals = val_ds@Wv+bv
  gemmkv_k<64, 64, 32, 32, 32><<<dim3(32, 12, 2), 256, 0, stream>>>(
      key_ds, 768, WkT, 768, phi_k, 768, bk_c, 768,
      1572864, 589824, 1572864, 768);

  // 5. per-(b,n) KV state + z (sT/zbuf overwrite key_ds/val_ds — dead after step 4)
  kv_state_k<<<dim3(384), 256, 0, stream>>>(phi_k, vals, sT, zbuf);

  // 6. a_v = (phi_q @ s) * 1/(phi_q.z+eps), fused qz, in-place
  attn_av_k<<<dim3(8, 384), 256, 0, stream>>>(phi_q, sT, zbuf);

  // 7. out = a_v @ Wout + bout (fp32 C)
  gemm97_k<0, true><<<dim3(128, 6), 256, 0, stream>>>(
      a_v, 768, WoutT, 768, out, 768, bout_c, 768);
}